// Round 1
// baseline (8686.716 us; speedup 1.0000x reference)
//
#include <hip/hip_runtime.h>

#define HH 1024
#define FOURH 4096
#define BB 256
#define TT 192
#define WARM 64
#define NSTEP 256        // 128 warm + 127 decode + 1 final-output-only iteration
#define UPB 16           // units per block
#define LDS_BYTES 150144

typedef _Float16 f16;
typedef _Float16 f16x8 __attribute__((ext_vector_type(8)));
typedef float    f32x4 __attribute__((ext_vector_type(4)));

// workspace layout (bytes):
//   [0, 1 MiB)            : h ping-pong buffers, f16 [2][256][1024]
//   [1 MiB, 1 MiB+1 KiB)  : barrier counters (256 u32)
//   [1 MiB+1 KiB, +256KiB): pred partials f32 [2][4 mg][64 row][2 k][64 nblk]
#define H_ELEMS (BB*HH)
#define CTR_OFF (2*H_ELEMS*2)
#define PP_OFF  (CTR_OFF + 1024)

__global__ void init_ws(unsigned int* ws) {
  int i = blockIdx.x * 256 + threadIdx.x;
  if (i < (CTR_OFF + 1024) / 4) ws[i] = 0u;
}

__device__ __forceinline__ float fsig(float x) { return 1.0f / (1.0f + __expf(-x)); }
__device__ __forceinline__ float ftanh(float x) {
  float ax = fabsf(x);
  float e  = __expf(-2.0f * ax);
  float t  = (1.0f - e) / (1.0f + e);
  return x < 0.0f ? -t : t;
}

__launch_bounds__(256, 1)
__global__ void lstm_persist(const float* __restrict__ inp,
                             const float* __restrict__ Wx,
                             const float* __restrict__ Wh,
                             const float* __restrict__ bias,
                             const float* __restrict__ Wd,
                             const float* __restrict__ bdp,
                             float* __restrict__ out,
                             unsigned char* __restrict__ ws)
{
  extern __shared__ char smem[];
  f16*   Wl     = (f16*)smem;                    // 65536 halfs = 128 KiB, B-frag swizzled
  float* z_lds  = (float*)(smem + 131072);       // 64 x 68 fp32
  float* x_sh   = z_lds + 64 * 68;               // 64 x 2
  float* mask_sh= x_sh + 128;                    // 64
  float* wx0_sh = mask_sh + 64;                  // 64
  float* wx1_sh = wx0_sh + 64;                   // 64
  float* b_sh   = wx1_sh + 64;                   // 64
  float* wd_sh  = b_sh + 64;                     // 32

  f16*          hbuf = (f16*)ws;
  unsigned int* ctr  = (unsigned int*)(ws + CTR_OFF);
  float*        pp   = (float*)(ws + PP_OFF);

  const int tid  = threadIdx.x;
  const int bx   = blockIdx.x;
  const int mg   = bx >> 6;         // 4 batch groups of 64 rows
  const int nblk = bx & 63;         // 64 unit-groups of 16 units
  const int ublk = nblk * UPB;

  // ---------------- prologue: stage Wh slice into LDS in B-fragment order ----------------
  {
    const int wrow = tid >> 6;           // 0..3
    const int l    = tid & 63;
    const int gate = l >> 4;             // 0..3
    const int u    = l & 15;
    const int gcol = gate * HH + ublk + u;
    for (int rb = 0; rb < 256; rb += 8) {
      float v[8];
#pragma unroll
      for (int ii = 0; ii < 8; ++ii) {
        int r = (rb + ii) * 4 + wrow;
        v[ii] = Wh[r * FOURH + gcol];
      }
#pragma unroll
      for (int ii = 0; ii < 8; ++ii) {
        int r = (rb + ii) * 4 + wrow;
        int kk = r >> 5, sub = r & 31, q = sub >> 3, j = sub & 7;
        // frag layout: B[k = 32*kk + 8*q + j][n = u] for n-frag 'gate'
        Wl[((kk * 4 + gate) * 64 + (q * 16 + u)) * 8 + j] = (f16)v[ii];
      }
    }
    if (tid < 64) {
      int g2 = tid >> 4, u2 = tid & 15;
      int gc = g2 * HH + ublk + u2;
      wx0_sh[tid] = Wx[gc];
      wx1_sh[tid] = Wx[FOURH + gc];
      b_sh[tid]   = bias[gc];
    }
    if (tid < UPB) {
      wd_sh[tid * 2 + 0] = Wd[(ublk + tid) * 2 + 0];
      wd_sh[tid * 2 + 1] = Wd[(ublk + tid) * 2 + 1];
    }
  }
  __syncthreads();

  // per-thread cell state: unit u_ep, rows r0 + 16q
  const int u_ep = tid & 15;
  const int r0   = tid >> 4;
  float c_reg[4] = {0.f, 0.f, 0.f, 0.f};
  float h_reg[4] = {0.f, 0.f, 0.f, 0.f};

  const int wid  = tid >> 6;
  const int wm   = wid >> 1, wn = wid & 1;
  const int lane = tid & 63;
  const int lm   = lane & 15;          // row within fragment
  const int lq   = lane >> 4;          // k-quad

  const float bd0 = bdp[0], bd1 = bdp[1];

  for (int s = 0; s < NSTEP; ++s) {
    const bool decode = (s >= 128);

    // ---------------- phase A: produce x_t ----------------
    if (decode) {
      if (tid < 128) {
        int row = tid >> 1, k = tid & 1;
        const float* p = pp + ((((s + 1) & 1) * 4 + mg) * 64 + row) * 128 + k * 64;
        float a0 = 0.f, a1 = 0.f, a2 = 0.f, a3 = 0.f;
#pragma unroll
        for (int nb = 0; nb < 64; nb += 16) {
          f32x4 v0 = *(const f32x4*)(p + nb);
          f32x4 v1 = *(const f32x4*)(p + nb + 4);
          f32x4 v2 = *(const f32x4*)(p + nb + 8);
          f32x4 v3 = *(const f32x4*)(p + nb + 12);
          a0 += (v0.x + v0.y) + (v0.z + v0.w);
          a1 += (v1.x + v1.y) + (v1.z + v1.w);
          a2 += (v2.x + v2.y) + (v2.z + v2.w);
          a3 += (v3.x + v3.y) + (v3.z + v3.w);
        }
        float pr = ((a0 + a1) + (a2 + a3)) + (k ? bd1 : bd0);
        x_sh[row * 2 + k] = pr;
        if (nblk == 0) out[((mg * 64 + row) * 128 + (s - 128)) * 2 + k] = pr;
      }
      if (s == NSTEP - 1) break;   // uniform across the whole grid
    } else {
      if (tid < 64) {
        int row = tid;
        const float* ip = inp + ((mg * 64 + row) * TT + (WARM + s)) * 2;
        float i0 = ip[0], i1 = ip[1];
        bool m = (i0 != -1.0f) || (i1 != -1.0f);
        x_sh[row * 2 + 0] = m ? i0 : 0.0f;
        x_sh[row * 2 + 1] = m ? i1 : 0.0f;
        mask_sh[row]      = m ? 1.0f : 0.0f;
      }
    }

    // ---------------- phase B: z = h @ Wh via MFMA ----------------
    const f16* hb    = hbuf + (s & 1) * H_ELEMS;
    f16*       hnext = hbuf + ((s + 1) & 1) * H_ELEMS;

    f32x4 acc00 = {0.f,0.f,0.f,0.f}, acc01 = {0.f,0.f,0.f,0.f};
    f32x4 acc10 = {0.f,0.f,0.f,0.f}, acc11 = {0.f,0.f,0.f,0.f};

    const f16* arow0 = hb + (mg * 64 + 32 * wm + lm) * HH + 8 * lq;
    const f16* arow1 = arow0 + 16 * HH;
    const f16* bbase = Wl + ((2 * wn) * 64 + lane) * 8;

#pragma unroll 4
    for (int kk = 0; kk < 32; ++kk) {
      f16x8 a0 = *(const f16x8*)(arow0 + 32 * kk);
      f16x8 a1 = *(const f16x8*)(arow1 + 32 * kk);
      f16x8 b0 = *(const f16x8*)(bbase + kk * (4 * 64 * 8));
      f16x8 b1 = *(const f16x8*)(bbase + kk * (4 * 64 * 8) + 64 * 8);
      acc00 = __builtin_amdgcn_mfma_f32_16x16x32_f16(a0, b0, acc00, 0, 0, 0);
      acc01 = __builtin_amdgcn_mfma_f32_16x16x32_f16(a0, b1, acc01, 0, 0, 0);
      acc10 = __builtin_amdgcn_mfma_f32_16x16x32_f16(a1, b0, acc10, 0, 0, 0);
      acc11 = __builtin_amdgcn_mfma_f32_16x16x32_f16(a1, b1, acc11, 0, 0, 0);
    }

    {
      int colb = 32 * wn;
      int rowb = 32 * wm + lq * 4;   // C/D: row = 4*(lane>>4)+reg, col = lane&15
#pragma unroll
      for (int reg = 0; reg < 4; ++reg) {
        z_lds[(rowb + reg) * 68      + colb      + lm] = acc00[reg];
        z_lds[(rowb + reg) * 68      + colb + 16 + lm] = acc01[reg];
        z_lds[(rowb + reg + 16) * 68 + colb      + lm] = acc10[reg];
        z_lds[(rowb + reg + 16) * 68 + colb + 16 + lm] = acc11[reg];
      }
    }
    __syncthreads();

    // ---------------- phase C: gates + state update + pred partials ----------------
    const bool wr_pred = (s >= 127);
#pragma unroll
    for (int q = 0; q < 4; ++q) {
      int row = r0 + 16 * q;
      float x0 = x_sh[row * 2], x1 = x_sh[row * 2 + 1];
      float zi = z_lds[row * 68 +      u_ep] + x0 * wx0_sh[     u_ep] + x1 * wx1_sh[     u_ep] + b_sh[     u_ep];
      float zf = z_lds[row * 68 + 16 + u_ep] + x0 * wx0_sh[16 + u_ep] + x1 * wx1_sh[16 + u_ep] + b_sh[16 + u_ep];
      float zg = z_lds[row * 68 + 32 + u_ep] + x0 * wx0_sh[32 + u_ep] + x1 * wx1_sh[32 + u_ep] + b_sh[32 + u_ep];
      float zo = z_lds[row * 68 + 48 + u_ep] + x0 * wx0_sh[48 + u_ep] + x1 * wx1_sh[48 + u_ep] + b_sh[48 + u_ep];
      float ig = fsig(zi), fg = fsig(zf), gg = ftanh(zg), og = fsig(zo);
      float cn = fg * c_reg[q] + ig * gg;
      float hn = og * ftanh(cn);
      if (!decode) {
        bool m = mask_sh[row] > 0.5f;
        cn = m ? cn : c_reg[q];
        hn = m ? hn : h_reg[q];
      }
      c_reg[q] = cn; h_reg[q] = hn;
      hnext[(mg * 64 + row) * HH + ublk + u_ep] = (f16)hn;

      if (wr_pred) {
        float p0 = hn * wd_sh[u_ep * 2 + 0];
        float p1 = hn * wd_sh[u_ep * 2 + 1];
#pragma unroll
        for (int m2 = 1; m2 < 16; m2 <<= 1) {
          p0 += __shfl_xor(p0, m2, 64);
          p1 += __shfl_xor(p1, m2, 64);
        }
        if (u_ep == 0) {
          float* dst = pp + (((s & 1) * 4 + mg) * 64 + row) * 128;
          dst[nblk]      = p0;
          dst[64 + nblk] = p1;
        }
      }
    }

    // ---------------- grid barrier (256 co-resident blocks, 1/CU) ----------------
    __syncthreads();
    if (tid == 0) {
      __threadfence();
      atomicAdd(&ctr[s], 1u);
      int guard = 0;
      while (__hip_atomic_load(&ctr[s], __ATOMIC_RELAXED, __HIP_MEMORY_SCOPE_AGENT) < 256u) {
        __builtin_amdgcn_s_sleep(8);
        if (++guard > 300000) break;   // bail-out: never hang the bench
      }
      __threadfence();
    }
    __syncthreads();
  }
}

extern "C" void kernel_launch(void* const* d_in, const int* in_sizes, int n_in,
                              void* d_out, int out_size, void* d_ws, size_t ws_size,
                              hipStream_t stream) {
  const float* inp = (const float*)d_in[0];
  const float* Wx  = (const float*)d_in[1];
  const float* Wh  = (const float*)d_in[2];
  const float* b   = (const float*)d_in[3];
  const float* Wd  = (const float*)d_in[4];
  const float* bd  = (const float*)d_in[5];
  float* out = (float*)d_out;
  unsigned char* ws = (unsigned char*)d_ws;

  init_ws<<<1025, 256, 0, stream>>>((unsigned int*)ws);

  hipFuncSetAttribute((const void*)lstm_persist,
                      hipFuncAttributeMaxDynamicSharedMemorySize, LDS_BYTES);
  lstm_persist<<<256, 256, LDS_BYTES, stream>>>(inp, Wx, b ? Wh : Wh, b, Wd, bd, out, ws);
}

// Round 2
// 3854.889 us; speedup vs baseline: 2.2534x; 2.2534x over previous
//
#include <hip/hip_runtime.h>

#define HH 1024
#define FOURH 4096
#define BB 256
#define TT 192
#define WARM 64
#define NSTEP 256        // 128 warm + 127 decode + 1 final-output-only iteration
#define UPB 16           // units per block
#define LDS_BYTES 150144

typedef _Float16 f16;
typedef _Float16 f16x4 __attribute__((ext_vector_type(4)));
typedef _Float16 f16x8 __attribute__((ext_vector_type(8)));
typedef float    f32x4 __attribute__((ext_vector_type(4)));
typedef unsigned long long u64;

// workspace layout (bytes):
//   [0, 1 MiB)      : h ping-pong buffers, f16 [2][256][1024]
//   [1 MiB, +1 KiB) : per-block step flags (256 u32, monotonic = step+1)
//   [+1 KiB, +256K) : pred partials f32 [2][4 mg][64 row][2 k][64 nblk]
#define H_ELEMS (BB*HH)
#define FLG_OFF (2*H_ELEMS*2)
#define PP_OFF  (FLG_OFF + 1024)

__global__ void init_ws(unsigned int* ws) {
  int i = blockIdx.x * 256 + threadIdx.x;
  if (i < (FLG_OFF + 1024) / 4) ws[i] = 0u;
}

__device__ __forceinline__ float fsig(float x) { return 1.0f / (1.0f + __expf(-x)); }
__device__ __forceinline__ float ftanh(float x) {
  float ax = fabsf(x);
  float e  = __expf(-2.0f * ax);
  float t  = (1.0f - e) / (1.0f + e);
  return x < 0.0f ? -t : t;
}

// coherent (agent-scope, write-through / L2-bypass) accessors — no cache flushes
__device__ __forceinline__ u64 cld64(const void* p) {
  return __hip_atomic_load((const u64*)p, __ATOMIC_RELAXED, __HIP_MEMORY_SCOPE_AGENT);
}
__device__ __forceinline__ void cst32(void* p, unsigned int v) {
  __hip_atomic_store((unsigned int*)p, v, __ATOMIC_RELAXED, __HIP_MEMORY_SCOPE_AGENT);
}
__device__ __forceinline__ void cstf(float* p, float v) {
  __hip_atomic_store(p, v, __ATOMIC_RELAXED, __HIP_MEMORY_SCOPE_AGENT);
}
__device__ __forceinline__ float lo_f(u64 v) { return __uint_as_float((unsigned int)v); }
__device__ __forceinline__ float hi_f(u64 v) { return __uint_as_float((unsigned int)(v >> 32)); }
__device__ __forceinline__ unsigned int umin4(unsigned int a, unsigned int b,
                                              unsigned int c, unsigned int d) {
  unsigned int x = a < b ? a : b;
  unsigned int y = c < d ? c : d;
  return x < y ? x : y;
}

__launch_bounds__(256, 1)
__global__ void lstm_persist(const float* __restrict__ inp,
                             const float* __restrict__ Wx,
                             const float* __restrict__ Wh,
                             const float* __restrict__ bias,
                             const float* __restrict__ Wd,
                             const float* __restrict__ bdp,
                             float* __restrict__ out,
                             unsigned char* __restrict__ ws)
{
  extern __shared__ char smem[];
  f16*   Wl     = (f16*)smem;                    // 65536 halfs = 128 KiB, B-frag swizzled
  float* z_lds  = (float*)(smem + 131072);       // 64 x 68 fp32
  float* x_sh   = z_lds + 64 * 68;               // 64 x 2
  float* mask_sh= x_sh + 128;                    // 64
  float* wx0_sh = mask_sh + 64;                  // 64
  float* wx1_sh = wx0_sh + 64;                   // 64
  float* b_sh   = wx1_sh + 64;                   // 64
  float* wd_sh  = b_sh + 64;                     // 32

  f16*          hbuf = (f16*)ws;
  unsigned int* flg  = (unsigned int*)(ws + FLG_OFF);
  float*        pp   = (float*)(ws + PP_OFF);

  const int tid  = threadIdx.x;
  const int bx   = blockIdx.x;
  const int mg   = bx >> 6;         // 4 batch groups of 64 rows
  const int nblk = bx & 63;         // 64 unit-groups of 16 units
  const int ublk = nblk * UPB;

  // ---------------- prologue: stage Wh slice into LDS in B-fragment order ----------------
  {
    const int wrow = tid >> 6;           // 0..3
    const int l    = tid & 63;
    const int gate = l >> 4;             // 0..3
    const int u    = l & 15;
    const int gcol = gate * HH + ublk + u;
    for (int rb = 0; rb < 256; rb += 8) {
      float v[8];
#pragma unroll
      for (int ii = 0; ii < 8; ++ii) {
        int r = (rb + ii) * 4 + wrow;
        v[ii] = Wh[r * FOURH + gcol];
      }
#pragma unroll
      for (int ii = 0; ii < 8; ++ii) {
        int r = (rb + ii) * 4 + wrow;
        int kk = r >> 5, sub = r & 31, q = sub >> 3, j = sub & 7;
        // frag layout: B[k = 32*kk + 8*q + j][n = u] for n-frag 'gate'
        Wl[((kk * 4 + gate) * 64 + (q * 16 + u)) * 8 + j] = (f16)v[ii];
      }
    }
    if (tid < 64) {
      int g2 = tid >> 4, u2 = tid & 15;
      int gc = g2 * HH + ublk + u2;
      wx0_sh[tid] = Wx[gc];
      wx1_sh[tid] = Wx[FOURH + gc];
      b_sh[tid]   = bias[gc];
    }
    if (tid < UPB) {
      wd_sh[tid * 2 + 0] = Wd[(ublk + tid) * 2 + 0];
      wd_sh[tid * 2 + 1] = Wd[(ublk + tid) * 2 + 1];
    }
  }
  __syncthreads();

  // per-thread cell state (phase C ownership): unit u_ep, rows r0 + 16q
  const int u_ep = tid & 15;
  const int r0   = tid >> 4;
  float c_reg[4] = {0.f, 0.f, 0.f, 0.f};
  float h_reg[4] = {0.f, 0.f, 0.f, 0.f};

  const int wid  = tid >> 6;           // wave id: owns rows 16*wid..16*wid+15, all 64 cols
  const int lane = tid & 63;
  const int lm   = lane & 15;
  const int lq   = lane >> 4;

  const float bd0 = bdp[0], bd1 = bdp[1];

  for (int s = 0; s < NSTEP; ++s) {
    const bool decode = (s >= 128);

    // ---------------- phase A: produce x_t ----------------
    if (decode) {
      if (tid < 128) {
        int row = tid >> 1, k = tid & 1;
        const u64* p = (const u64*)(pp + ((((s + 1) & 1) * 4 + mg) * 64 + row) * 128 + k * 64);
        float s0 = 0.f, s1 = 0.f, s2 = 0.f, s3 = 0.f;
#pragma unroll
        for (int i = 0; i < 32; i += 4) {
          u64 v0 = cld64(p + i), v1 = cld64(p + i + 1);
          u64 v2 = cld64(p + i + 2), v3 = cld64(p + i + 3);
          s0 += lo_f(v0) + hi_f(v0);
          s1 += lo_f(v1) + hi_f(v1);
          s2 += lo_f(v2) + hi_f(v2);
          s3 += lo_f(v3) + hi_f(v3);
        }
        float pr = ((s0 + s1) + (s2 + s3)) + (k ? bd1 : bd0);
        x_sh[row * 2 + k] = pr;
        if (nblk == 0) out[((mg * 64 + row) * 128 + (s - 128)) * 2 + k] = pr;
      }
      if (s == NSTEP - 1) break;   // uniform across the whole grid
    } else {
      if (tid < 64) {
        int row = tid;
        const float* ip = inp + ((mg * 64 + row) * TT + (WARM + s)) * 2;
        float i0 = ip[0], i1 = ip[1];
        bool m = (i0 != -1.0f) || (i1 != -1.0f);
        x_sh[row * 2 + 0] = m ? i0 : 0.0f;
        x_sh[row * 2 + 1] = m ? i1 : 0.0f;
        mask_sh[row]      = m ? 1.0f : 0.0f;
      }
    }

    // ---------------- phase B: z = h @ Wh via MFMA ----------------
    // each wave: 16 unique rows x 64 cols; A from global (coherent loads,
    // double-buffered chunks of 8 k-steps), B from LDS.
    const f16* hb    = hbuf + (s & 1) * H_ELEMS;
    f16*       hnext = hbuf + ((s + 1) & 1) * H_ELEMS;

    f32x4 acc0 = {0.f,0.f,0.f,0.f}, acc1 = {0.f,0.f,0.f,0.f};
    f32x4 acc2 = {0.f,0.f,0.f,0.f}, acc3 = {0.f,0.f,0.f,0.f};

    const u64* ap = (const u64*)(hb + (mg * 64 + 16 * wid + lm) * HH + 8 * lq);
    // per k-step kk: 16B A-frag at u64 offset 8*kk

    u64 q[2][16];
#pragma unroll
    for (int i = 0; i < 8; ++i) {
      q[0][2*i]   = cld64(ap + 8*i);
      q[0][2*i+1] = cld64(ap + 8*i + 1);
    }
#pragma unroll
    for (int c = 0; c < 4; ++c) {
      const int cur = c & 1, nxt = cur ^ 1;
      if (c < 3) {
#pragma unroll
        for (int i = 0; i < 8; ++i) {
          q[nxt][2*i]   = cld64(ap + 64*(c+1) + 8*i);
          q[nxt][2*i+1] = cld64(ap + 64*(c+1) + 8*i + 1);
        }
      }
#pragma unroll
      for (int i = 0; i < 8; ++i) {
        const int kk = 8*c + i;
        f16x4 lo = __builtin_bit_cast(f16x4, q[cur][2*i]);
        f16x4 hi = __builtin_bit_cast(f16x4, q[cur][2*i+1]);
        f16x8 a  = __builtin_shufflevector(lo, hi, 0,1,2,3,4,5,6,7);
        const f16* bb = Wl + kk * 2048 + lane * 8;
        f16x8 b0 = *(const f16x8*)(bb);
        f16x8 b1 = *(const f16x8*)(bb + 512);
        f16x8 b2 = *(const f16x8*)(bb + 1024);
        f16x8 b3 = *(const f16x8*)(bb + 1536);
        acc0 = __builtin_amdgcn_mfma_f32_16x16x32_f16(a, b0, acc0, 0, 0, 0);
        acc1 = __builtin_amdgcn_mfma_f32_16x16x32_f16(a, b1, acc1, 0, 0, 0);
        acc2 = __builtin_amdgcn_mfma_f32_16x16x32_f16(a, b2, acc2, 0, 0, 0);
        acc3 = __builtin_amdgcn_mfma_f32_16x16x32_f16(a, b3, acc3, 0, 0, 0);
      }
    }

    {
      int rowb = 16 * wid + 4 * lq;    // C/D: row = 4*(lane>>4)+reg, col = lane&15
#pragma unroll
      for (int r = 0; r < 4; ++r) {
        z_lds[(rowb + r) * 68      + lm] = acc0[r];
        z_lds[(rowb + r) * 68 + 16 + lm] = acc1[r];
        z_lds[(rowb + r) * 68 + 32 + lm] = acc2[r];
        z_lds[(rowb + r) * 68 + 48 + lm] = acc3[r];
      }
    }
    __syncthreads();

    // ---------------- phase C: gates + state update + pred partials ----------------
    const bool wr_pred = (s >= 127);
#pragma unroll
    for (int q4 = 0; q4 < 4; ++q4) {
      int row = r0 + 16 * q4;
      float x0 = x_sh[row * 2], x1 = x_sh[row * 2 + 1];
      float zi = z_lds[row * 68 +      u_ep] + x0 * wx0_sh[     u_ep] + x1 * wx1_sh[     u_ep] + b_sh[     u_ep];
      float zf = z_lds[row * 68 + 16 + u_ep] + x0 * wx0_sh[16 + u_ep] + x1 * wx1_sh[16 + u_ep] + b_sh[16 + u_ep];
      float zg = z_lds[row * 68 + 32 + u_ep] + x0 * wx0_sh[32 + u_ep] + x1 * wx1_sh[32 + u_ep] + b_sh[32 + u_ep];
      float zo = z_lds[row * 68 + 48 + u_ep] + x0 * wx0_sh[48 + u_ep] + x1 * wx1_sh[48 + u_ep] + b_sh[48 + u_ep];
      float ig = fsig(zi), fg = fsig(zf), gg = ftanh(zg), og = fsig(zo);
      float cn = fg * c_reg[q4] + ig * gg;
      float hn = og * ftanh(cn);
      if (!decode) {
        bool m = mask_sh[row] > 0.5f;
        cn = m ? cn : c_reg[q4];
        hn = m ? hn : h_reg[q4];
      }
      c_reg[q4] = cn; h_reg[q4] = hn;

      // packed write-through h store (2 halfs per u32, even lanes store)
      f16 hf = (f16)hn;
      unsigned int lo16    = (unsigned int)__builtin_bit_cast(unsigned short, hf);
      unsigned int partner = (unsigned int)__shfl_xor((int)lo16, 1, 64);
      if ((u_ep & 1) == 0) {
        unsigned int pair = lo16 | (partner << 16);
        cst32((void*)(hnext + (mg * 64 + row) * HH + ublk + u_ep), pair);
      }

      if (wr_pred) {
        float p0 = hn * wd_sh[u_ep * 2 + 0];
        float p1 = hn * wd_sh[u_ep * 2 + 1];
#pragma unroll
        for (int m2 = 1; m2 < 16; m2 <<= 1) {
          p0 += __shfl_xor(p0, m2, 64);
          p1 += __shfl_xor(p1, m2, 64);
        }
        if (u_ep == 0) {
          float* dst = pp + (((s & 1) * 4 + mg) * 64 + row) * 128;
          cstf(dst + nblk,      p0);
          cstf(dst + 64 + nblk, p1);
        }
      }
    }

    // ---------------- grid barrier: flag array, no RMW, no cache flush ----------------
    __syncthreads();                          // drains vmcnt(0) in every wave: stores visible
    if (tid == 0) cst32(flg + bx, (unsigned int)(s + 1));
    if (tid < 64) {
      const u64* fp = (const u64*)flg;
      const unsigned int tgt = (unsigned int)(s + 1);
      int guard = 0;
      for (;;) {
        u64 a = cld64(fp + 2 * tid);
        u64 b = cld64(fp + 2 * tid + 1);
        unsigned int mn = umin4((unsigned int)a, (unsigned int)(a >> 32),
                                (unsigned int)b, (unsigned int)(b >> 32));
        if (__all(mn >= tgt)) break;
        if (++guard > 200000) break;          // bail-out: never hang the bench
        __builtin_amdgcn_s_sleep(1);
      }
    }
    asm volatile("" ::: "memory");
    __syncthreads();
  }
}

extern "C" void kernel_launch(void* const* d_in, const int* in_sizes, int n_in,
                              void* d_out, int out_size, void* d_ws, size_t ws_size,
                              hipStream_t stream) {
  const float* inp = (const float*)d_in[0];
  const float* Wx  = (const float*)d_in[1];
  const float* Wh  = (const float*)d_in[2];
  const float* b   = (const float*)d_in[3];
  const float* Wd  = (const float*)d_in[4];
  const float* bd  = (const float*)d_in[5];
  float* out = (float*)d_out;
  unsigned char* ws = (unsigned char*)d_ws;

  init_ws<<<1025, 256, 0, stream>>>((unsigned int*)ws);

  hipFuncSetAttribute((const void*)lstm_persist,
                      hipFuncAttributeMaxDynamicSharedMemorySize, LDS_BYTES);
  lstm_persist<<<256, 256, LDS_BYTES, stream>>>(inp, Wx, Wh, b, Wd, bd, out, ws);
}